// Round 3
// baseline (213.462 us; speedup 1.0000x reference)
//
#include <hip/hip_runtime.h>
#include <hip/hip_bf16.h>

#define NPOS 2744      // 14^3
#define BB 4
#define BNTOT (BB*NPOS)   // 10976
#define RELVOL 19683   // 27^3
#define CPAD 178       // vfrag c-slots: 176 real (2816 m) + 2 pad
#define NPAIR 1372

typedef __bf16 bf16x8 __attribute__((ext_vector_type(8)));
typedef float f32x16 __attribute__((ext_vector_type(16)));

// ---- workspace layout (bytes) ----
#define WS_Q  0u           // f32 [4][64][2744]
#define WS_K  2809856u     // f32 [4][16][2744]  (dead after k_lamc2; reused below)
#define WS_V  3512320u     // f32 [4][16][2744]
#define WS_ST 4214784u     // f32 [160] scale/shift
#define WS_SA 4215424u     // f32 [192] stats accum: ssum[96], ssq[96]
#define WS_LA 4216192u     // f32 [1088] lc accum: [4][16][17]
#define WS_LC 4220544u     // f32 [4][16][16]
#define WS_E2 4224640u     // u16 [19683][16]  bf16 E table, k-MINOR
#define WS_VF WS_K                     // uint4 [2][178][64]  (alias of dead kws)
#define WS_PM (WS_K + 364544u)         // u16 [2880] position codes

__device__ inline unsigned short f2bf(float f) {
  unsigned int u = __float_as_uint(f);
  return (unsigned short)((u + 0x7fffu + ((u >> 16) & 1u)) >> 16);
}

// ---------------- P1: qkv projections + fused BN-stat partials ----------------
// grid = 43 nb * 3 cg; cg0: q0..31, cg1: q32..63, cg2: k0..15 + v0..15
__global__ __launch_bounds__(256) void k_qkv(const float* __restrict__ x,
    const float* __restrict__ Wq, const float* __restrict__ Wk, const float* __restrict__ Wv,
    float* __restrict__ qws, float* __restrict__ kws, float* __restrict__ vws,
    float* __restrict__ sa) {
  int cg = blockIdx.x % 3, nb = blockIdx.x / 3;
  int tid = threadIdx.x;
  int gid = nb * 256 + tid;
  bool act = gid < BNTOT;
  int g2 = act ? gid : 0;
  int b = g2 / NPOS, n = g2 - b * NPOS;
  const float* xp = x + (size_t)b * 64 * NPOS + n;

  __shared__ float lsum[32], lss[32];
  if (tid < 32) { lsum[tid] = 0.f; lss[tid] = 0.f; }
  __syncthreads();

  const float* wb = (cg == 0) ? Wq : ((cg == 1) ? Wq + 2048 : Wk);
  const float* wb2 = Wv - 1024;   // so wb2 + j*64 == Wv + (j-16)*64
  float acc[32];
#pragma unroll
  for (int j = 0; j < 32; ++j) acc[j] = 0.f;
  if (act) {
    for (int c = 0; c < 64; c += 4) {
      float x0 = xp[(c + 0) * NPOS], x1 = xp[(c + 1) * NPOS];
      float x2 = xp[(c + 2) * NPOS], x3 = xp[(c + 3) * NPOS];
#pragma unroll
      for (int j = 0; j < 32; ++j) {
        const float* wr = (cg == 2 && j >= 16) ? (wb2 + j * 64) : (wb + j * 64);
        float4 w = *(const float4*)(wr + c);
        acc[j] += w.x * x0 + w.y * x1 + w.z * x2 + w.w * x3;
      }
    }
#pragma unroll
    for (int j = 0; j < 32; ++j) {
      if (cg < 2)       qws[((size_t)b * 64 + cg * 32 + j) * NPOS + n] = acc[j];
      else if (j < 16)  kws[((size_t)b * 16 + j) * NPOS + n] = acc[j];
      else              vws[((size_t)b * 16 + (j - 16)) * NPOS + n] = acc[j];
    }
    // stats partials (q channels and v channels only)
#pragma unroll
    for (int j = 0; j < 32; ++j) {
      if (cg < 2 || j >= 16) {
        atomicAdd(&lsum[j], acc[j]);
        atomicAdd(&lss[j], acc[j] * acc[j]);
      }
    }
  }
  __syncthreads();
  if (tid < 32) {
    int slot = (cg == 0) ? tid : ((cg == 1) ? 32 + tid : ((tid >= 16) ? 80 + (tid - 16) : -1));
    if (slot >= 0) { atomicAdd(&sa[slot], lsum[tid]); atomicAdd(&sa[96 + slot], lss[tid]); }
  }
}

// ---------------- P2: lambda_c partials (no-max softmax) + st finalize ----------------
// blocks 0..255: (b,kc,seg); block 256: finalize st from stats accumulators
__global__ __launch_bounds__(256) void k_lamc2(const float* __restrict__ kws,
    const float* __restrict__ vws, const float* __restrict__ sa,
    const float* __restrict__ gq, const float* __restrict__ bq,
    const float* __restrict__ gv, const float* __restrict__ bv,
    float* __restrict__ st, float* __restrict__ lcacc) {
  int bid = blockIdx.x;
  int tid = threadIdx.x;
  if (bid == 256) {
    if (tid < 80) {
      int ch = (tid < 64) ? tid : 80 + (tid - 64);
      float mean = sa[ch] / (float)BNTOT;
      float var = sa[96 + ch] / (float)BNTOT - mean * mean;
      float inv = rsqrtf(var + 1e-5f);
      float g, be;
      if (tid < 64) { g = gq[tid]; be = bq[tid]; } else { g = gv[tid - 64]; be = bv[tid - 64]; }
      float sc = g * inv, sh = be - mean * sc;
      if (tid < 64) { st[tid] = sc; st[64 + tid] = sh; }
      else { st[128 + (tid - 64)] = sc; st[144 + (tid - 64)] = sh; }
    }
    return;
  }
  int b = bid >> 6, kc = (bid >> 2) & 15, seg = bid & 3;
  const float* kp = kws + ((size_t)b * 16 + kc) * NPOS;
  const float* vp = vws + (size_t)b * 16 * NPOS;
  float s = 0.f, acc[16];
#pragma unroll
  for (int v = 0; v < 16; ++v) acc[v] = 0.f;
  int m0 = seg * 686;
  for (int m = m0 + tid; m < m0 + 686; m += 256) {
    float e = __expf(kp[m]);
    s += e;
#pragma unroll
    for (int v = 0; v < 16; ++v) acc[v] += e * vp[(size_t)v * NPOS + m];
  }
#pragma unroll
  for (int o = 32; o > 0; o >>= 1) {
    s += __shfl_xor(s, o, 64);
#pragma unroll
    for (int v = 0; v < 16; ++v) acc[v] += __shfl_xor(acc[v], o, 64);
  }
  __shared__ float red[17][4];
  int wid = tid >> 6;
  if ((tid & 63) == 0) { red[16][wid] = s; for (int v = 0; v < 16; ++v) red[v][wid] = acc[v]; }
  __syncthreads();
  if (tid < 17) {
    float tot = red[tid][0] + red[tid][1] + red[tid][2] + red[tid][3];
    atomicAdd(lcacc + ((size_t)b * 16 + kc) * 17 + tid, tot);
  }
}

// ---------------- P3: tables (ebt2, vfrag, pmcg) + lc finalize ----------------
__global__ __launch_bounds__(256) void k_conv(const float* __restrict__ rpe,
    const float* __restrict__ vws, const float* __restrict__ st,
    const float* __restrict__ lcacc, unsigned short* __restrict__ ebt2,
    uint4* __restrict__ vfrag, unsigned short* __restrict__ pmcg,
    float* __restrict__ lc) {
  int tid = blockIdx.x * 256 + threadIdx.x;
  int stride = gridDim.x * 256;
  const int N1 = 16 * RELVOL;        // 314928
  const int N2 = 2 * CPAD * 64;      // 22784
  const int N3 = 2880;               // pmcg
  const int N4 = 1024;               // lc
  const int TOT = N1 + N2 + N3 + N4;
  for (int idx = tid; idx < TOT; idx += stride) {
    if (idx < N1) {
      ebt2[idx] = f2bf(rpe[idx]);
    } else if (idx < N1 + N2) {
      int t = idx - N1;
      int ct = t / (CPAD * 64); int r = t - ct * (CPAD * 64);
      int c = r >> 6, l = r & 63;
      int b = ct * 2 + ((l >> 4) & 1), v = l & 15;
      int mu0 = c * 16 + (l >> 5) * 8;
      float sc = st[128 + v], sh = st[144 + v];
      unsigned int wds[4];
#pragma unroll
      for (int i = 0; i < 4; ++i) {
        float f0 = 0.f, f1 = 0.f;
        int m0 = mu0 + 2 * i, m1 = m0 + 1;
        if (m0 < NPOS) f0 = vws[((size_t)b * 16 + v) * NPOS + m0] * sc + sh;
        if (m1 < NPOS) f1 = vws[((size_t)b * 16 + v) * NPOS + m1] * sc + sh;
        wds[i] = (unsigned int)f2bf(f0) | ((unsigned int)f2bf(f1) << 16);
      }
      vfrag[(ct * CPAD + c) * 64 + l] = make_uint4(wds[0], wds[1], wds[2], wds[3]);
    } else if (idx < N1 + N2 + N3) {
      int i3 = idx - N1 - N2;
      int m = (i3 < NPOS) ? i3 : (NPOS - 1);
      int zm = m / 196; int t2 = m - zm * 196; int ym = t2 / 14; int xm = t2 - ym * 14;
      pmcg[i3] = (unsigned short)(zm * 729 + ym * 27 + xm);
    } else {
      int t = idx - N1 - N2 - N3;
      int b = t >> 8, kc = (t >> 4) & 15, v = t & 15;
      const float* la = lcacc + ((size_t)b * 16 + kc) * 17;
      float S = la[16];
      lc[((size_t)b * 16 + kc) * 16 + v] = st[128 + v] * (la[v] / S) + st[144 + v];
    }
  }
}

// ---------------- P4: main lambda_p MFMA kernel ----------------
// 1372 blocks * 256 thr (4 waves). One n-pair per block; wave w covers m-steps
// [w*22, w*22+22) of 32 m each. LDS-free main loop; tree reduction at end.
#define PKHI(hi, lo) __builtin_amdgcn_perm(__float_as_uint(hi), __float_as_uint(lo), 0x07060302u)

__global__ __launch_bounds__(256) void k_lam(const unsigned short* __restrict__ ebt2,
    const unsigned short* __restrict__ pmcg, const uint4* __restrict__ vfrag,
    const float* __restrict__ qws, const float* __restrict__ st,
    const float* __restrict__ lc, float* __restrict__ out) {
  __shared__ float red[4096];
  int tid = threadIdx.x;
  int w = tid >> 6, l = tid & 63;
  int np = blockIdx.x;
  int n0 = np * 2, n1 = n0 + 1;
  int zn = n0 / 196; int t0 = n0 - zn * 196; int yn = t0 / 14; int xn = t0 - yn * 14;
  int base0 = 9841 - (zn * 729 + yn * 27 + xn);
  int zn1 = n1 / 196; int t1 = n1 - zn1 * 196; int yn1 = t1 / 14; int xn1 = t1 - yn1 * 14;
  int base1 = 9841 - (zn1 * 729 + yn1 * 27 + xn1);

  int p = l & 31;
  int fl = (p & 19) | ((p & 4) << 1) | ((p & 8) >> 1);   // swap bits 2<->3
  int kh = l >> 5;

  // identity B-fragments for the transpose MFMAs
  uint4 bi = make_uint4(0, 0, 0, 0);
  int j0 = (l & 15) - kh * 8;
  if (j0 >= 0 && j0 < 8) {
    unsigned int one = 0x3F80u << (16 * (j0 & 1));
    if ((j0 >> 1) == 0) bi.x = one; else if ((j0 >> 1) == 1) bi.y = one;
    else if ((j0 >> 1) == 2) bi.z = one; else bi.w = one;
  }
  uint4 zero4 = make_uint4(0, 0, 0, 0);
  uint4 bI0 = (l & 16) ? zero4 : bi;   // fills A-rows 0..15  (n0)
  uint4 bI1 = (l & 16) ? bi : zero4;   // fills A-rows 16..31 (n1)

  f32x16 acc0, acc1, zz;
#pragma unroll
  for (int i = 0; i < 16; ++i) { acc0[i] = 0.f; acc1[i] = 0.f; zz[i] = 0.f; }

  int dS = w * 22, dE = dS + 22;
  const unsigned short* pmp = pmcg + fl;

  unsigned short pmc_ = pmp[dS * 32];
  unsigned short pmn = pmp[(dS + 1) * 32];
  uint4 A0, A1, B0, B1, B2, B3;
  {
    int e0 = (int)pmc_ + base0, e1 = (int)pmc_ + base1;
    A0 = *(const uint4*)(ebt2 + e0 * 16 + kh * 8);
    A1 = *(const uint4*)(ebt2 + e1 * 16 + kh * 8);
    const uint4* vf = vfrag + (size_t)(2 * dS) * 64 + l;
    B0 = vf[0]; B1 = vf[64]; B2 = vf[CPAD * 64]; B3 = vf[CPAD * 64 + 64];
  }
  for (int d = dS; d < dE; ++d) {
    unsigned short pm2 = pmp[(d + 2) * 32];
    uint4 nA0, nA1, nB0, nB1, nB2, nB3;
    {
      int e0 = (int)pmn + base0, e1 = (int)pmn + base1;
      nA0 = *(const uint4*)(ebt2 + e0 * 16 + kh * 8);
      nA1 = *(const uint4*)(ebt2 + e1 * 16 + kh * 8);
      const uint4* vf = vfrag + (size_t)(2 * (d + 1)) * 64 + l;
      nB0 = vf[0]; nB1 = vf[64]; nB2 = vf[CPAD * 64]; nB3 = vf[CPAD * 64 + 64];
    }
    __builtin_amdgcn_s_setprio(1);
    // transpose through the matrix pipe
    f32x16 tr = __builtin_amdgcn_mfma_f32_32x32x16_bf16(
        __builtin_bit_cast(bf16x8, A0), __builtin_bit_cast(bf16x8, bI0), zz, 0, 0, 0);
    tr = __builtin_amdgcn_mfma_f32_32x32x16_bf16(
        __builtin_bit_cast(bf16x8, A1), __builtin_bit_cast(bf16x8, bI1), tr, 0, 0, 0);
    // pack exact-bf16 f32 pairs -> two A fragments
    uint4 alo, ahi;
    alo.x = PKHI(tr[1], tr[0]);  alo.y = PKHI(tr[3], tr[2]);
    alo.z = PKHI(tr[5], tr[4]);  alo.w = PKHI(tr[7], tr[6]);
    ahi.x = PKHI(tr[9], tr[8]);  ahi.y = PKHI(tr[11], tr[10]);
    ahi.z = PKHI(tr[13], tr[12]); ahi.w = PKHI(tr[15], tr[14]);
    acc0 = __builtin_amdgcn_mfma_f32_32x32x16_bf16(
        __builtin_bit_cast(bf16x8, alo), __builtin_bit_cast(bf16x8, B0), acc0, 0, 0, 0);
    acc0 = __builtin_amdgcn_mfma_f32_32x32x16_bf16(
        __builtin_bit_cast(bf16x8, ahi), __builtin_bit_cast(bf16x8, B1), acc0, 0, 0, 0);
    acc1 = __builtin_amdgcn_mfma_f32_32x32x16_bf16(
        __builtin_bit_cast(bf16x8, alo), __builtin_bit_cast(bf16x8, B2), acc1, 0, 0, 0);
    acc1 = __builtin_amdgcn_mfma_f32_32x32x16_bf16(
        __builtin_bit_cast(bf16x8, ahi), __builtin_bit_cast(bf16x8, B3), acc1, 0, 0, 0);
    __builtin_amdgcn_s_setprio(0);
    A0 = nA0; A1 = nA1; B0 = nB0; B1 = nB1; B2 = nB2; B3 = nB3;
    pmc_ = pmn; pmn = pm2;
  }

  // ---- 2-stage tree reduction across 4 waves ----
  if (w >= 2) {
    int base = (w - 2) * 2048;
#pragma unroll
    for (int r = 0; r < 16; ++r) {
      red[base + r * 64 + l] = acc0[r];
      red[base + 1024 + r * 64 + l] = acc1[r];
    }
  }
  __syncthreads();
  if (w < 2) {
    int base = w * 2048;
#pragma unroll
    for (int r = 0; r < 16; ++r) {
      acc0[r] += red[base + r * 64 + l];
      acc1[r] += red[base + 1024 + r * 64 + l];
    }
  }
  __syncthreads();
  if (w == 1) {
#pragma unroll
    for (int r = 0; r < 16; ++r) { red[r * 64 + l] = acc0[r]; red[1024 + r * 64 + l] = acc1[r]; }
  }
  __syncthreads();
  if (w == 0) {
#pragma unroll
    for (int r = 0; r < 16; ++r) { acc0[r] += red[r * 64 + l]; acc1[r] += red[1024 + r * 64 + l]; }
    int sig = kh;
    int bsel = (l >> 4) & 1, v = l & 15;
#pragma unroll
    for (int ct = 0; ct < 2; ++ct) {
      int b = ct * 2 + bsel;
      float lam[16];
#pragma unroll
      for (int r = 0; r < 16; ++r) {
        int kk = (r & 3) + 4 * sig + 8 * ((r >> 2) & 1);
        lam[r] = (ct ? acc1[r] : acc0[r]) + lc[((size_t)b * 16 + kk) * 16 + v];
      }
#pragma unroll
      for (int ns = 0; ns < 2; ++ns) {
        int n = np * 2 + ns;
#pragma unroll
        for (int h = 0; h < 4; ++h) {
          float part = 0.f;
#pragma unroll
          for (int rr = 0; rr < 8; ++rr) {
            int kk = (rr & 3) + 4 * sig + 8 * ((rr >> 2) & 1);
            int ch = h * 16 + kk;
            float qv = qws[((size_t)b * 64 + ch) * NPOS + n] * st[ch] + st[64 + ch];
            part += qv * lam[ns * 8 + rr];
          }
          part += __shfl_xor(part, 32, 64);
          if (sig == 0) out[((size_t)b * 64 + h * 16 + v) * NPOS + n] = part;
        }
      }
    }
  }
}

extern "C" void kernel_launch(void* const* d_in, const int* in_sizes, int n_in,
                              void* d_out, int out_size, void* d_ws, size_t ws_size,
                              hipStream_t stream) {
  const float* x   = (const float*)d_in[0];
  const float* Wq  = (const float*)d_in[1];
  const float* Wk  = (const float*)d_in[2];
  const float* Wv  = (const float*)d_in[3];
  const float* rpe = (const float*)d_in[4];
  const float* gq  = (const float*)d_in[5];
  const float* bq  = (const float*)d_in[6];
  const float* gv  = (const float*)d_in[7];
  const float* bv  = (const float*)d_in[8];
  float* out = (float*)d_out;
  char* ws = (char*)d_ws;
  float* qws = (float*)(ws + WS_Q);
  float* kws = (float*)(ws + WS_K);
  float* vws = (float*)(ws + WS_V);
  float* st  = (float*)(ws + WS_ST);
  float* sa  = (float*)(ws + WS_SA);
  float* la  = (float*)(ws + WS_LA);
  float* lcp = (float*)(ws + WS_LC);
  unsigned short* ebt2 = (unsigned short*)(ws + WS_E2);
  uint4* vfrag = (uint4*)(ws + WS_VF);
  unsigned short* pmcg = (unsigned short*)(ws + WS_PM);

  // zero the atomic accumulators (sa + la are contiguous: 192 + 1088 floats)
  hipMemsetAsync(ws + WS_SA, 0, (192 + 1088) * sizeof(float), stream);
  k_qkv<<<129, 256, 0, stream>>>(x, Wq, Wk, Wv, qws, kws, vws, sa);
  k_lamc2<<<257, 256, 0, stream>>>(kws, vws, sa, gq, bq, gv, bv, st, la);
  k_conv<<<512, 256, 0, stream>>>(rpe, vws, st, la, ebt2, vfrag, pmcg, lcp);
  k_lam<<<NPAIR, 256, 0, stream>>>(ebt2, pmcg, vfrag, qws, st, lcp, out);
}

// Round 5
// 88.322 us; speedup vs baseline: 2.4169x; 2.4169x over previous
//
#include <hip/hip_runtime.h>
#include <hip/hip_bf16.h>

#define NPOS 2744      // 14^3
#define BB 4
#define BNTOT (BB*NPOS)   // 10976
#define RELVOL 19683   // 27^3
#define CPAD 178       // vfrag c-slots: 176 real (2816 m) + 2 pad
#define NPAIR 1372

typedef __bf16 bf16x8 __attribute__((ext_vector_type(8)));
typedef float f32x16 __attribute__((ext_vector_type(16)));

// ---- workspace layout (bytes) ----
#define WS_Q  0u           // f32 [4][64][2744]
#define WS_K  2809856u     // f32 [4][16][2744]  (dead after k_sl; reused below)
#define WS_V  3512320u     // f32 [4][16][2744]
#define WS_ST 4214784u     // f32 [160] scale/shift
#define WS_LA 4216192u     // f32 [1088] lc accum: [4][16][17]
#define WS_LC 4220544u     // f32 [4][16][16]
#define WS_E2 4224640u     // u16 [19683][16]  bf16 E table, k-MINOR
#define WS_VF WS_K                     // uint4 [2][178][64]  (alias of dead kws)
#define WS_PM (WS_K + 364544u)         // u16 [2880] position codes

__device__ inline unsigned short f2bf(float f) {
  unsigned int u = __float_as_uint(f);
  return (unsigned short)((u + 0x7fffu + ((u >> 16) & 1u)) >> 16);
}

// ---------------- P1: qkv projections ----------------
// grid = 43 nb * 12 channel-groups of 8; each group lives in exactly one of Wq/Wk/Wv.
__global__ __launch_bounds__(256) void k_qkv(const float* __restrict__ x,
    const float* __restrict__ Wq, const float* __restrict__ Wk, const float* __restrict__ Wv,
    float* __restrict__ qws, float* __restrict__ kws, float* __restrict__ vws) {
  int cg = blockIdx.x % 12, nb = blockIdx.x / 12;
  int gid = nb * 256 + threadIdx.x;
  if (gid >= BNTOT) return;
  int b = gid / NPOS, n = gid - b * NPOS;
  const float* xp = x + (size_t)b * 64 * NPOS + n;
  int ch0 = cg * 8;
  const float* wbase;
  float* obase;
  if (ch0 < 64)      { wbase = Wq + ch0 * 64;        obase = qws + ((size_t)b * 64 + ch0) * NPOS + n; }
  else if (ch0 < 80) { wbase = Wk + (ch0 - 64) * 64; obase = kws + ((size_t)b * 16 + (ch0 - 64)) * NPOS + n; }
  else               { wbase = Wv + (ch0 - 80) * 64; obase = vws + ((size_t)b * 16 + (ch0 - 80)) * NPOS + n; }

  float acc[8];
#pragma unroll
  for (int j = 0; j < 8; ++j) acc[j] = 0.f;
  for (int c = 0; c < 64; c += 4) {
    float x0 = xp[(c + 0) * NPOS], x1 = xp[(c + 1) * NPOS];
    float x2 = xp[(c + 2) * NPOS], x3 = xp[(c + 3) * NPOS];
#pragma unroll
    for (int j = 0; j < 8; ++j) {
      float4 w = *(const float4*)(wbase + j * 64 + c);
      acc[j] += w.x * x0 + w.y * x1 + w.z * x2 + w.w * x3;
    }
  }
#pragma unroll
  for (int j = 0; j < 8; ++j) obase[(size_t)j * NPOS] = acc[j];
}

// ---------------- P2: BN stats+finalize (blocks 0..79) | lambda_c partials (80..335) ----------------
__global__ __launch_bounds__(256) void k_sl(const float* __restrict__ qws,
    const float* __restrict__ kws, const float* __restrict__ vws,
    const float* __restrict__ gq, const float* __restrict__ bq,
    const float* __restrict__ gv, const float* __restrict__ bv,
    float* __restrict__ st, float* __restrict__ lcacc) {
  int bid = blockIdx.x;
  int tid = threadIdx.x;
  int wid = tid >> 6;
  __shared__ float red[17][4];
  if (bid < 80) {
    int ch = bid;
    const float* p = (ch < 64) ? (qws + (size_t)ch * NPOS) : (vws + (size_t)(ch - 64) * NPOS);
    size_t pstride = (ch < 64) ? (size_t)64 * NPOS : (size_t)16 * NPOS;
    float s = 0.f, ss = 0.f;
    for (int b = 0; b < 4; ++b) {
      const float* pp = p + b * pstride;
      for (int n = tid; n < NPOS; n += 256) { float v = pp[n]; s += v; ss += v * v; }
    }
#pragma unroll
    for (int o = 32; o > 0; o >>= 1) { s += __shfl_xor(s, o, 64); ss += __shfl_xor(ss, o, 64); }
    if ((tid & 63) == 0) { red[0][wid] = s; red[1][wid] = ss; }
    __syncthreads();
    if (tid == 0) {
      float S = red[0][0] + red[0][1] + red[0][2] + red[0][3];
      float SS = red[1][0] + red[1][1] + red[1][2] + red[1][3];
      float mean = S / (float)BNTOT;
      float var = SS / (float)BNTOT - mean * mean;
      float inv = rsqrtf(var + 1e-5f);
      float g, be;
      if (ch < 64) { g = gq[ch]; be = bq[ch]; } else { g = gv[ch - 64]; be = bv[ch - 64]; }
      float sc = g * inv, sh = be - mean * sc;
      if (ch < 64) { st[ch] = sc; st[64 + ch] = sh; }
      else { st[128 + (ch - 64)] = sc; st[144 + (ch - 64)] = sh; }
    }
  } else {
    int bid2 = bid - 80;
    int b = bid2 >> 6, kc = (bid2 >> 2) & 15, seg = bid2 & 3;
    const float* kp = kws + ((size_t)b * 16 + kc) * NPOS;
    const float* vp = vws + (size_t)b * 16 * NPOS;
    float s = 0.f, acc[16];
#pragma unroll
    for (int v = 0; v < 16; ++v) acc[v] = 0.f;
    int m0 = seg * 686;
    for (int m = m0 + tid; m < m0 + 686; m += 256) {
      float e = __expf(kp[m]);
      s += e;
#pragma unroll
      for (int v = 0; v < 16; ++v) acc[v] += e * vp[(size_t)v * NPOS + m];
    }
#pragma unroll
    for (int o = 32; o > 0; o >>= 1) {
      s += __shfl_xor(s, o, 64);
#pragma unroll
      for (int v = 0; v < 16; ++v) acc[v] += __shfl_xor(acc[v], o, 64);
    }
    if ((tid & 63) == 0) { red[16][wid] = s; for (int v = 0; v < 16; ++v) red[v][wid] = acc[v]; }
    __syncthreads();
    if (tid < 17) {
      float tot = red[tid][0] + red[tid][1] + red[tid][2] + red[tid][3];
      atomicAdd(lcacc + ((size_t)b * 16 + kc) * 17 + tid, tot);
    }
  }
}

// ---------------- P3: tables (ebt2, vfrag, pmcg) + lc finalize ----------------
__global__ __launch_bounds__(256) void k_conv(const float* __restrict__ rpe,
    const float* __restrict__ vws, const float* __restrict__ st,
    const float* __restrict__ lcacc, unsigned short* __restrict__ ebt2,
    uint4* __restrict__ vfrag, unsigned short* __restrict__ pmcg,
    float* __restrict__ lc) {
  int tid = blockIdx.x * 256 + threadIdx.x;
  int stride = gridDim.x * 256;
  const int N1 = 16 * RELVOL;        // 314928
  const int N2 = 2 * CPAD * 64;      // 22784
  const int N3 = 2880;               // pmcg
  const int N4 = 1024;               // lc
  const int TOT = N1 + N2 + N3 + N4;
  for (int idx = tid; idx < TOT; idx += stride) {
    if (idx < N1) {
      ebt2[idx] = f2bf(rpe[idx]);
    } else if (idx < N1 + N2) {
      int t = idx - N1;
      int ct = t / (CPAD * 64); int r = t - ct * (CPAD * 64);
      int c = r >> 6, l = r & 63;
      int b = ct * 2 + ((l >> 4) & 1), v = l & 15;
      int mu0 = c * 16 + (l >> 5) * 8;
      float sc = st[128 + v], sh = st[144 + v];
      unsigned int wds[4];
#pragma unroll
      for (int i = 0; i < 4; ++i) {
        float f0 = 0.f, f1 = 0.f;
        int m0 = mu0 + 2 * i, m1 = m0 + 1;
        if (m0 < NPOS) f0 = vws[((size_t)b * 16 + v) * NPOS + m0] * sc + sh;
        if (m1 < NPOS) f1 = vws[((size_t)b * 16 + v) * NPOS + m1] * sc + sh;
        wds[i] = (unsigned int)f2bf(f0) | ((unsigned int)f2bf(f1) << 16);
      }
      vfrag[(ct * CPAD + c) * 64 + l] = make_uint4(wds[0], wds[1], wds[2], wds[3]);
    } else if (idx < N1 + N2 + N3) {
      int i3 = idx - N1 - N2;
      int m = (i3 < NPOS) ? i3 : (NPOS - 1);
      int zm = m / 196; int t2 = m - zm * 196; int ym = t2 / 14; int xm = t2 - ym * 14;
      pmcg[i3] = (unsigned short)(zm * 729 + ym * 27 + xm);
    } else {
      int t = idx - N1 - N2 - N3;
      int b = t >> 8, kc = (t >> 4) & 15, v = t & 15;
      const float* la = lcacc + ((size_t)b * 16 + kc) * 17;
      float S = la[16];
      lc[((size_t)b * 16 + kc) * 16 + v] = st[128 + v] * (la[v] / S) + st[144 + v];
    }
  }
}

// ---------------- P4: main lambda_p MFMA kernel ----------------
// 1372 blocks * 256 thr (4 waves). One n-pair per block; wave w covers m-steps
// [w*22, w*22+22) of 32 m each. LDS-free main loop; tree reduction at end.
#define PKHI(hi, lo) __builtin_amdgcn_perm(__float_as_uint(hi), __float_as_uint(lo), 0x07060302u)

__global__ __launch_bounds__(256) void k_lam(const unsigned short* __restrict__ ebt2,
    const unsigned short* __restrict__ pmcg, const uint4* __restrict__ vfrag,
    const float* __restrict__ qws, const float* __restrict__ st,
    const float* __restrict__ lc, float* __restrict__ out) {
  __shared__ float red[4096];
  int tid = threadIdx.x;
  int w = tid >> 6, l = tid & 63;
  int np = blockIdx.x;
  int n0 = np * 2, n1 = n0 + 1;
  int zn = n0 / 196; int t0 = n0 - zn * 196; int yn = t0 / 14; int xn = t0 - yn * 14;
  int base0 = 9841 - (zn * 729 + yn * 27 + xn);
  int zn1 = n1 / 196; int t1 = n1 - zn1 * 196; int yn1 = t1 / 14; int xn1 = t1 - yn1 * 14;
  int base1 = 9841 - (zn1 * 729 + yn1 * 27 + xn1);

  int p = l & 31;
  int fl = (p & 19) | ((p & 4) << 1) | ((p & 8) >> 1);   // swap bits 2<->3
  int kh = l >> 5;

  // identity B-fragments for the transpose MFMAs
  uint4 bi = make_uint4(0, 0, 0, 0);
  int j0 = (l & 15) - kh * 8;
  if (j0 >= 0 && j0 < 8) {
    unsigned int one = 0x3F80u << (16 * (j0 & 1));
    if ((j0 >> 1) == 0) bi.x = one; else if ((j0 >> 1) == 1) bi.y = one;
    else if ((j0 >> 1) == 2) bi.z = one; else bi.w = one;
  }
  uint4 zero4 = make_uint4(0, 0, 0, 0);
  uint4 bI0 = (l & 16) ? zero4 : bi;   // fills A-rows 0..15  (n0)
  uint4 bI1 = (l & 16) ? bi : zero4;   // fills A-rows 16..31 (n1)

  f32x16 acc0, acc1, zz;
#pragma unroll
  for (int i = 0; i < 16; ++i) { acc0[i] = 0.f; acc1[i] = 0.f; zz[i] = 0.f; }

  int dS = w * 22, dE = dS + 22;
  const unsigned short* pmp = pmcg + fl;

  unsigned short pmc_ = pmp[dS * 32];
  unsigned short pmn = pmp[(dS + 1) * 32];
  uint4 A0, A1, B0, B1, B2, B3;
  {
    int e0 = (int)pmc_ + base0, e1 = (int)pmc_ + base1;
    A0 = *(const uint4*)(ebt2 + e0 * 16 + kh * 8);
    A1 = *(const uint4*)(ebt2 + e1 * 16 + kh * 8);
    const uint4* vf = vfrag + (size_t)(2 * dS) * 64 + l;
    B0 = vf[0]; B1 = vf[64]; B2 = vf[CPAD * 64]; B3 = vf[CPAD * 64 + 64];
  }
  for (int d = dS; d < dE; ++d) {
    unsigned short pm2 = pmp[(d + 2) * 32];
    uint4 nA0, nA1, nB0, nB1, nB2, nB3;
    {
      int e0 = (int)pmn + base0, e1 = (int)pmn + base1;
      nA0 = *(const uint4*)(ebt2 + e0 * 16 + kh * 8);
      nA1 = *(const uint4*)(ebt2 + e1 * 16 + kh * 8);
      const uint4* vf = vfrag + (size_t)(2 * (d + 1)) * 64 + l;
      nB0 = vf[0]; nB1 = vf[64]; nB2 = vf[CPAD * 64]; nB3 = vf[CPAD * 64 + 64];
    }
    __builtin_amdgcn_s_setprio(1);
    // transpose through the matrix pipe
    f32x16 tr = __builtin_amdgcn_mfma_f32_32x32x16_bf16(
        __builtin_bit_cast(bf16x8, A0), __builtin_bit_cast(bf16x8, bI0), zz, 0, 0, 0);
    tr = __builtin_amdgcn_mfma_f32_32x32x16_bf16(
        __builtin_bit_cast(bf16x8, A1), __builtin_bit_cast(bf16x8, bI1), tr, 0, 0, 0);
    // pack exact-bf16 f32 pairs -> two A fragments
    uint4 alo, ahi;
    alo.x = PKHI(tr[1], tr[0]);  alo.y = PKHI(tr[3], tr[2]);
    alo.z = PKHI(tr[5], tr[4]);  alo.w = PKHI(tr[7], tr[6]);
    ahi.x = PKHI(tr[9], tr[8]);  ahi.y = PKHI(tr[11], tr[10]);
    ahi.z = PKHI(tr[13], tr[12]); ahi.w = PKHI(tr[15], tr[14]);
    acc0 = __builtin_amdgcn_mfma_f32_32x32x16_bf16(
        __builtin_bit_cast(bf16x8, alo), __builtin_bit_cast(bf16x8, B0), acc0, 0, 0, 0);
    acc0 = __builtin_amdgcn_mfma_f32_32x32x16_bf16(
        __builtin_bit_cast(bf16x8, ahi), __builtin_bit_cast(bf16x8, B1), acc0, 0, 0, 0);
    acc1 = __builtin_amdgcn_mfma_f32_32x32x16_bf16(
        __builtin_bit_cast(bf16x8, alo), __builtin_bit_cast(bf16x8, B2), acc1, 0, 0, 0);
    acc1 = __builtin_amdgcn_mfma_f32_32x32x16_bf16(
        __builtin_bit_cast(bf16x8, ahi), __builtin_bit_cast(bf16x8, B3), acc1, 0, 0, 0);
    __builtin_amdgcn_s_setprio(0);
    A0 = nA0; A1 = nA1; B0 = nB0; B1 = nB1; B2 = nB2; B3 = nB3;
    pmc_ = pmn; pmn = pm2;
  }

  // ---- 2-stage tree reduction across 4 waves ----
  if (w >= 2) {
    int base = (w - 2) * 2048;
#pragma unroll
    for (int r = 0; r < 16; ++r) {
      red[base + r * 64 + l] = acc0[r];
      red[base + 1024 + r * 64 + l] = acc1[r];
    }
  }
  __syncthreads();
  if (w < 2) {
    int base = w * 2048;
#pragma unroll
    for (int r = 0; r < 16; ++r) {
      acc0[r] += red[base + r * 64 + l];
      acc1[r] += red[base + 1024 + r * 64 + l];
    }
  }
  __syncthreads();
  if (w == 1) {
#pragma unroll
    for (int r = 0; r < 16; ++r) { red[r * 64 + l] = acc0[r]; red[1024 + r * 64 + l] = acc1[r]; }
  }
  __syncthreads();
  if (w == 0) {
#pragma unroll
    for (int r = 0; r < 16; ++r) { acc0[r] += red[r * 64 + l]; acc1[r] += red[1024 + r * 64 + l]; }
    int sig = kh;
    int bsel = (l >> 4) & 1, v = l & 15;
#pragma unroll
    for (int ct = 0; ct < 2; ++ct) {
      int b = ct * 2 + bsel;
      float lam[16];
#pragma unroll
      for (int r = 0; r < 16; ++r) {
        int kk = (r & 3) + 4 * sig + 8 * ((r >> 2) & 1);
        lam[r] = (ct ? acc1[r] : acc0[r]) + lc[((size_t)b * 16 + kk) * 16 + v];
      }
#pragma unroll
      for (int ns = 0; ns < 2; ++ns) {
        int n = np * 2 + ns;
#pragma unroll
        for (int h = 0; h < 4; ++h) {
          float part = 0.f;
#pragma unroll
          for (int rr = 0; rr < 8; ++rr) {
            int kk = (rr & 3) + 4 * sig + 8 * ((rr >> 2) & 1);
            int ch = h * 16 + kk;
            float qv = qws[((size_t)b * 64 + ch) * NPOS + n] * st[ch] + st[64 + ch];
            part += qv * lam[ns * 8 + rr];
          }
          part += __shfl_xor(part, 32, 64);
          if (sig == 0) out[((size_t)b * 64 + h * 16 + v) * NPOS + n] = part;
        }
      }
    }
  }
}

extern "C" void kernel_launch(void* const* d_in, const int* in_sizes, int n_in,
                              void* d_out, int out_size, void* d_ws, size_t ws_size,
                              hipStream_t stream) {
  const float* x   = (const float*)d_in[0];
  const float* Wq  = (const float*)d_in[1];
  const float* Wk  = (const float*)d_in[2];
  const float* Wv  = (const float*)d_in[3];
  const float* rpe = (const float*)d_in[4];
  const float* gq  = (const float*)d_in[5];
  const float* bq  = (const float*)d_in[6];
  const float* gv  = (const float*)d_in[7];
  const float* bv  = (const float*)d_in[8];
  float* out = (float*)d_out;
  char* ws = (char*)d_ws;
  float* qws = (float*)(ws + WS_Q);
  float* kws = (float*)(ws + WS_K);
  float* vws = (float*)(ws + WS_V);
  float* st  = (float*)(ws + WS_ST);
  float* la  = (float*)(ws + WS_LA);
  float* lcp = (float*)(ws + WS_LC);
  unsigned short* ebt2 = (unsigned short*)(ws + WS_E2);
  uint4* vfrag = (uint4*)(ws + WS_VF);
  unsigned short* pmcg = (unsigned short*)(ws + WS_PM);

  // zero the lambda_c atomic accumulator
  hipMemsetAsync(ws + WS_LA, 0, 1088 * sizeof(float), stream);
  k_qkv<<<516, 256, 0, stream>>>(x, Wq, Wk, Wv, qws, kws, vws);
  k_sl<<<336, 256, 0, stream>>>(qws, kws, vws, gq, bq, gv, bv, st, la);
  k_conv<<<512, 256, 0, stream>>>(rpe, vws, st, la, ebt2, vfrag, pmcg, lcp);
  k_lam<<<NPAIR, 256, 0, stream>>>(ebt2, pmcg, vfrag, qws, st, lcp, out);
}